// Round 5
// baseline (148.522 us; speedup 1.0000x reference)
//
#include <hip/hip_runtime.h>
#include <hip/hip_bf16.h>

#define B_N  4096
#define K_D  1024
#define TILE 128
#define BK   64
#define KT   (K_D / BK)              // 16 K-tiles
#define NT   (B_N / TILE)            // 32 tile-rows
#define NBLK (NT * (NT + 1) / 2)     // 528 upper-triangular tiles (= 66*8, XCD-divisible)

typedef __bf16 bf16x8 __attribute__((ext_vector_type(8)));
typedef float  f32x4  __attribute__((ext_vector_type(4)));

// round-to-nearest-even float -> bf16 bits (inputs are finite normals; no NaN path needed)
__device__ __forceinline__ unsigned short f2bf(float x) {
    union { float f; unsigned int u; } v; v.f = x;
    unsigned int r = v.u + 0x7fffu + ((v.u >> 16) & 1u);
    return (unsigned short)(r >> 16);
}

// One block (256 threads) per row: compute L2 norm, write bf16 normalized row.
// Also zeroes rowsum[row], possum, and the completion ticket (workspace is poisoned
// between iterations, so every slot we read-accumulate must be re-zeroed here).
__global__ void normalize_bf16(const float* __restrict__ f, unsigned short* __restrict__ fnb,
                               float* __restrict__ rowsum) {
    const int row = blockIdx.x;
    const int tid = threadIdx.x;
    float4 v = ((const float4*)(f + (size_t)row * K_D))[tid];
    float s = v.x * v.x + v.y * v.y + v.z * v.z + v.w * v.w;
#pragma unroll
    for (int m = 1; m < 64; m <<= 1) s += __shfl_xor(s, m, 64);
    __shared__ float wsum[4];
    if ((tid & 63) == 0) wsum[tid >> 6] = s;
    __syncthreads();
    float tot = wsum[0] + wsum[1] + wsum[2] + wsum[3];
    float scale = 1.0f / fmaxf(sqrtf(tot), 1e-12f);
    ushort4 o;
    o.x = f2bf(v.x * scale); o.y = f2bf(v.y * scale);
    o.z = f2bf(v.z * scale); o.w = f2bf(v.w * scale);
    ((ushort4*)(fnb + (size_t)row * K_D))[tid] = o;
    if (tid == 0) rowsum[row] = 0.0f;
    if (row == 0 && tid == 1) rowsum[B_N] = 0.0f;                         // possum
    if (row == 0 && tid == 2) ((unsigned int*)rowsum)[B_N + 1] = 0u;      // ticket
}

// LDS tile layout: [row][8 slots of 16B], slot XOR-swizzled by (row&7) (T2; measured
// 0 bank conflicts in rounds 2-4). Stored via pre-swizzled GLOBAL source
// (global_load_lds writes linearly); read with the same XOR.
__device__ __forceinline__ const bf16x8* lds_frag(const unsigned short* base, int row, int ks) {
    return (const bf16x8*)((const char*)base + row * (BK * 2) + (((ks ^ row) & 7) << 4));
}

// Upper-triangular 128x128 tiles of sim = fn*fn^T (symmetric), 528 blocks.
// Off-diagonal tile (bi<bj): computed once, credited twice (row sums + quad-reduced
// column sums + pospart*2). Diagonal: B-stage skipped, frags read from As.
// Sync structure = round-1's measured-best (single-buffer, __syncthreads); T2-swizzled
// staging; T1 XCD-chunked block order. The LAST block to finish (completion ticket)
// computes the final loss in-place -- no separate finalize dispatch.
__global__ void gemm_exp_reduce(const unsigned short* __restrict__ fnb,
                                const int* __restrict__ labels,
                                float* __restrict__ rowsum,
                                float* __restrict__ possum,
                                float* __restrict__ out) {
    __shared__ __align__(16) unsigned short As[TILE * BK]; // 16 KB
    __shared__ __align__(16) unsigned short Bs[TILE * BK]; // 16 KB
    __shared__ int   rlab[TILE];
    __shared__ int   clab[TILE];
    __shared__ float posred[4];
    __shared__ unsigned int ticket_s;

    // XCD-bijective swizzle (T1): 528 = 66*8 -> 66 contiguous triangular indices/XCD
    // (consecutive t share bi -> A-panel L2 reuse within an XCD).
    const int t0 = (blockIdx.x & 7) * (NBLK / 8) + (blockIdx.x >> 3);
    int t  = t0;
    int bi = 0;
    while (t >= NT - bi) { t -= NT - bi; ++bi; }
    const int  bj   = bi + t;
    const bool diag = (bi == bj);

    const int row0 = bi * TILE, col0 = bj * TILE;
    const int tid  = threadIdx.x;
    const int lane = tid & 63, wave = tid >> 6;
    const int wr = wave >> 1, wc = wave & 1;          // 2x2 wave grid
    const int quad = lane >> 4, l15 = lane & 15;

    if (tid < TILE) rlab[tid] = labels[row0 + tid];
    else            clab[tid - TILE] = labels[col0 + tid - TILE];

    const unsigned short* Ag = fnb + (size_t)row0 * K_D;
    const unsigned short* Bg = fnb + (size_t)col0 * K_D;

    f32x4 acc[4][4];
#pragma unroll
    for (int i = 0; i < 4; ++i)
#pragma unroll
        for (int j = 0; j < 4; ++j) {
            f32x4 z = {0.f, 0.f, 0.f, 0.f};
            acc[i][j] = z;
        }

    for (int k0 = 0; k0 < K_D; k0 += BK) {
        // Stage A (and B when off-diag) as [128][64] bf16. Chunk c = ld*256+tid ->
        // LDS bytes [c*16,+16) (linear, lane-ordered, as global_load_lds requires);
        // global source column pre-swizzled: slot^(row&7).
#pragma unroll
        for (int ld = 0; ld < 4; ++ld) {
            int c  = ld * 256 + tid;
            int r  = c >> 3;
            int gc = ((c ^ r) & 7) << 3;
            __builtin_amdgcn_global_load_lds(
                (const unsigned int*)(Ag + (size_t)r * K_D + k0 + gc),
                (unsigned int*)&As[c * 8], 16, 0, 0);
            if (!diag)
                __builtin_amdgcn_global_load_lds(
                    (const unsigned int*)(Bg + (size_t)r * K_D + k0 + gc),
                    (unsigned int*)&Bs[c * 8], 16, 0, 0);
        }
        __syncthreads();

        const unsigned short* Bsrc = diag ? As : Bs;
        bf16x8 af[4][2], bq[4][2];
#pragma unroll
        for (int fr = 0; fr < 4; ++fr)
#pragma unroll
            for (int kk = 0; kk < 2; ++kk)
                af[fr][kk] = *lds_frag(As,   wr * 64 + fr * 16 + l15, kk * 4 + quad);
#pragma unroll
        for (int fc = 0; fc < 4; ++fc)
#pragma unroll
            for (int kk = 0; kk < 2; ++kk)
                bq[fc][kk] = *lds_frag(Bsrc, wc * 64 + fc * 16 + l15, kk * 4 + quad);
#pragma unroll
        for (int fr = 0; fr < 4; ++fr)
#pragma unroll
            for (int fc = 0; fc < 4; ++fc)
#pragma unroll
                for (int kk = 0; kk < 2; ++kk)
                    acc[fr][fc] = __builtin_amdgcn_mfma_f32_16x16x32_bf16(
                        af[fr][kk], bq[fc][kk], acc[fr][fc], 0, 0, 0);
        __syncthreads();
    }

    // Epilogue. C/D layout (m89/m91-verified): col = lane&15, row = quad*4 + reg.
    float pospart = 0.0f;
    float cs[4] = {0.f, 0.f, 0.f, 0.f};   // per-fc column sums (lane's column, over fr,r)
#pragma unroll
    for (int fr = 0; fr < 4; ++fr) {
        float rp[4] = {0.f, 0.f, 0.f, 0.f};
#pragma unroll
        for (int fc = 0; fc < 4; ++fc) {
            int c    = wc * 64 + fc * 16 + l15;
            int gcol = col0 + c;
            int cl   = clab[c];
#pragma unroll
            for (int r = 0; r < 4; ++r) {
                int rr   = wr * 64 + fr * 16 + quad * 4 + r;
                int grow = row0 + rr;
                float e  = (grow == gcol) ? 0.0f : __expf(acc[fr][fc][r] * 10.0f);
                rp[r] += e;
                cs[fc] += e;
                pospart += (rlab[rr] == cl) ? e : 0.0f;
            }
        }
        // row sums: reduce across the 16 columns (lanes sharing a quad)
#pragma unroll
        for (int r = 0; r < 4; ++r) {
            float v = rp[r];
            v += __shfl_xor(v, 1, 64);
            v += __shfl_xor(v, 2, 64);
            v += __shfl_xor(v, 4, 64);
            v += __shfl_xor(v, 8, 64);
            if (l15 == 0)
                atomicAdd(&rowsum[row0 + wr * 64 + fr * 16 + quad * 4 + r], v);
        }
    }
    if (!diag) {
        // column sums: reduce across the 4 quads (rows of this wave's 64-row band)
#pragma unroll
        for (int fc = 0; fc < 4; ++fc) {
            float v = cs[fc];
            v += __shfl_xor(v, 16, 64);
            v += __shfl_xor(v, 32, 64);
            if (quad == 0)
                atomicAdd(&rowsum[col0 + wc * 64 + fc * 16 + l15], v);
        }
        pospart *= 2.0f;   // mirror tile (bj,bi) contributes identically
    }
#pragma unroll
    for (int m = 1; m < 64; m <<= 1) pospart += __shfl_xor(pospart, m, 64);
    if (lane == 0) posred[wave] = pospart;
    __syncthreads();
    if (tid == 0)
        atomicAdd(possum, posred[0] + posred[1] + posred[2] + posred[3]);

    // ---- fused finalize: last block to finish computes the loss ----
    // Release: our rowsum/possum atomics complete before the ticket increment;
    // every block's increment is preceded by its own release fence, so the block
    // observing old == NBLK-1 knows ALL contributions are globally visible.
    __threadfence();
    if (tid == 0) ticket_s = atomicAdd((unsigned int*)(rowsum + B_N + 1), 1u);
    __syncthreads();
    if (ticket_s == NBLK - 1) {
        __threadfence();   // acquire side
        float s = 0.f;
        for (int i = tid; i < B_N; i += 256) s += logf(rowsum[i]);
#pragma unroll
        for (int m = 1; m < 64; m <<= 1) s += __shfl_xor(s, m, 64);
        if (lane == 0) posred[wave] = s;   // safe: all threads past previous posred use
        __syncthreads();
        if (tid == 0) {
            float tot = posred[0] + posred[1] + posred[2] + posred[3];
            // loss = mean_i log(rowsum_i) - log(possum)
            out[0] = tot / (float)B_N - logf(possum[0]);
        }
    }
}

extern "C" void kernel_launch(void* const* d_in, const int* in_sizes, int n_in,
                              void* d_out, int out_size, void* d_ws, size_t ws_size,
                              hipStream_t stream) {
    const float* features = (const float*)d_in[0];
    const int*   targets  = (const int*)d_in[1];
    float*       out      = (float*)d_out;

    // workspace layout: [bf16 fn: 8 MB][rowsum: 4096 f32][possum: 1 f32][ticket: 1 u32]
    unsigned short* fnb    = (unsigned short*)d_ws;
    float*          rowsum = (float*)((char*)d_ws + (size_t)B_N * K_D * sizeof(unsigned short));
    float*          possum = rowsum + B_N;

    normalize_bf16<<<B_N, 256, 0, stream>>>(features, fnb, rowsum);
    gemm_exp_reduce<<<NBLK, 256, 0, stream>>>(fnb, targets, rowsum, possum, out);
}

// Round 6
// 120.805 us; speedup vs baseline: 1.2294x; 1.2294x over previous
//
#include <hip/hip_runtime.h>
#include <hip/hip_bf16.h>

#define B_N  4096
#define K_D  1024
#define TILE 128
#define BK   64
#define NT   (B_N / TILE)            // 32 tile-rows
#define NBLK (NT * (NT + 1) / 2)     // 528 upper-triangular tiles

typedef __bf16 bf16x8 __attribute__((ext_vector_type(8)));
typedef float  f32x4  __attribute__((ext_vector_type(4)));

// round-to-nearest-even float -> bf16 bits (inputs are finite normals; no NaN path needed)
__device__ __forceinline__ unsigned short f2bf(float x) {
    union { float f; unsigned int u; } v; v.f = x;
    unsigned int r = v.u + 0x7fffu + ((v.u >> 16) & 1u);
    return (unsigned short)(r >> 16);
}

// One block (256 threads) per row: compute L2 norm, write bf16 normalized row.
// Also zeroes rowsum[row], possum, and the completion ticket (workspace is poisoned
// between harness iterations, so every accumulated slot must be re-zeroed here).
__global__ void normalize_bf16(const float* __restrict__ f, unsigned short* __restrict__ fnb,
                               float* __restrict__ rowsum) {
    const int row = blockIdx.x;
    const int tid = threadIdx.x;
    float4 v = ((const float4*)(f + (size_t)row * K_D))[tid];
    float s = v.x * v.x + v.y * v.y + v.z * v.z + v.w * v.w;
#pragma unroll
    for (int m = 1; m < 64; m <<= 1) s += __shfl_xor(s, m, 64);
    __shared__ float wsum[4];
    if ((tid & 63) == 0) wsum[tid >> 6] = s;
    __syncthreads();
    float tot = wsum[0] + wsum[1] + wsum[2] + wsum[3];
    float scale = 1.0f / fmaxf(sqrtf(tot), 1e-12f);
    ushort4 o;
    o.x = f2bf(v.x * scale); o.y = f2bf(v.y * scale);
    o.z = f2bf(v.z * scale); o.w = f2bf(v.w * scale);
    ((ushort4*)(fnb + (size_t)row * K_D))[tid] = o;
    if (tid == 0) rowsum[row] = 0.0f;
    if (row == 0 && tid == 1) rowsum[B_N] = 0.0f;                         // possum
    if (row == 0 && tid == 2) ((unsigned int*)rowsum)[B_N + 1] = 0u;      // ticket
}

// LDS tile layout: [row][8 slots of 16B], slot XOR-swizzled by (row&7) (T2; measured
// 0 bank conflicts rounds 2-5). Stored via pre-swizzled GLOBAL source (global_load_lds
// writes linearly); read with the same XOR.
__device__ __forceinline__ const bf16x8* lds_frag(const unsigned short* base, int row, int ks) {
    return (const bf16x8*)((const char*)base + row * (BK * 2) + (((ks ^ row) & 7) << 4));
}

// Upper-triangular 128x128 tiles of sim = fn*fn^T (symmetric), 528 blocks (round-1
// structure: single-buffer LDS 33.5 KB -> 4 blocks/CU, __syncthreads K-loop -- the
// 107.0 us anchor). Off-diagonal tile (bi<bj): computed once, credited twice (row
// sums + quad-reduced column sums + pospart*2). Diagonal: B-stage skipped.
// Fused finalize WITHOUT __threadfence (round 5 showed the agent fence emits L2
// writeback/invalidate: WRITE_SIZE +3.3MB, L2 thrash, gemm 45->85 us). Release =
// __syncthreads (drains vmcnt; device-scope atomics are then globally visible at
// the coherence point); acquire = agent-scope atomic loads (bypass stale caches).
__global__ void gemm_exp_reduce(const unsigned short* __restrict__ fnb,
                                const int* __restrict__ labels,
                                float* __restrict__ rowsum,
                                float* __restrict__ possum,
                                float* __restrict__ out) {
    __shared__ __align__(16) unsigned short As[TILE * BK]; // 16 KB
    __shared__ __align__(16) unsigned short Bs[TILE * BK]; // 16 KB
    __shared__ int   rlab[TILE];
    __shared__ int   clab[TILE];
    __shared__ float posred[4];
    __shared__ unsigned int ticket_s;

    // plain triangular decode (round-1 anchor had no XCD swizzle)
    int t  = blockIdx.x;
    int bi = 0;
    while (t >= NT - bi) { t -= NT - bi; ++bi; }
    const int  bj   = bi + t;
    const bool diag = (bi == bj);

    const int row0 = bi * TILE, col0 = bj * TILE;
    const int tid  = threadIdx.x;
    const int lane = tid & 63, wave = tid >> 6;
    const int wr = wave >> 1, wc = wave & 1;          // 2x2 wave grid
    const int quad = lane >> 4, l15 = lane & 15;

    if (tid < TILE) rlab[tid] = labels[row0 + tid];
    else            clab[tid - TILE] = labels[col0 + tid - TILE];

    const unsigned short* Ag = fnb + (size_t)row0 * K_D;
    const unsigned short* Bg = fnb + (size_t)col0 * K_D;

    f32x4 acc[4][4];
#pragma unroll
    for (int i = 0; i < 4; ++i)
#pragma unroll
        for (int j = 0; j < 4; ++j) {
            f32x4 z = {0.f, 0.f, 0.f, 0.f};
            acc[i][j] = z;
        }

    for (int k0 = 0; k0 < K_D; k0 += BK) {
        // Stage A (and B when off-diag) as [128][64] bf16. Chunk c = ld*256+tid ->
        // LDS bytes [c*16,+16) (linear, lane-ordered, as global_load_lds requires);
        // global source column pre-swizzled: slot^(row&7).
#pragma unroll
        for (int ld = 0; ld < 4; ++ld) {
            int c  = ld * 256 + tid;
            int r  = c >> 3;
            int gc = ((c ^ r) & 7) << 3;
            __builtin_amdgcn_global_load_lds(
                (const unsigned int*)(Ag + (size_t)r * K_D + k0 + gc),
                (unsigned int*)&As[c * 8], 16, 0, 0);
            if (!diag)
                __builtin_amdgcn_global_load_lds(
                    (const unsigned int*)(Bg + (size_t)r * K_D + k0 + gc),
                    (unsigned int*)&Bs[c * 8], 16, 0, 0);
        }
        __syncthreads();

        const unsigned short* Bsrc = diag ? As : Bs;
        bf16x8 af[4][2], bq[4][2];
#pragma unroll
        for (int fr = 0; fr < 4; ++fr)
#pragma unroll
            for (int kk = 0; kk < 2; ++kk)
                af[fr][kk] = *lds_frag(As,   wr * 64 + fr * 16 + l15, kk * 4 + quad);
#pragma unroll
        for (int fc = 0; fc < 4; ++fc)
#pragma unroll
            for (int kk = 0; kk < 2; ++kk)
                bq[fc][kk] = *lds_frag(Bsrc, wc * 64 + fc * 16 + l15, kk * 4 + quad);
#pragma unroll
        for (int fr = 0; fr < 4; ++fr)
#pragma unroll
            for (int fc = 0; fc < 4; ++fc)
#pragma unroll
                for (int kk = 0; kk < 2; ++kk)
                    acc[fr][fc] = __builtin_amdgcn_mfma_f32_16x16x32_bf16(
                        af[fr][kk], bq[fc][kk], acc[fr][fc], 0, 0, 0);
        __syncthreads();
    }

    // Epilogue. C/D layout (m89/m91-verified): col = lane&15, row = quad*4 + reg.
    float pospart = 0.0f;
    float cs[4] = {0.f, 0.f, 0.f, 0.f};   // per-fc column sums (lane's column, over fr,r)
#pragma unroll
    for (int fr = 0; fr < 4; ++fr) {
        float rp[4] = {0.f, 0.f, 0.f, 0.f};
#pragma unroll
        for (int fc = 0; fc < 4; ++fc) {
            int c    = wc * 64 + fc * 16 + l15;
            int gcol = col0 + c;
            int cl   = clab[c];
#pragma unroll
            for (int r = 0; r < 4; ++r) {
                int rr   = wr * 64 + fr * 16 + quad * 4 + r;
                int grow = row0 + rr;
                float e  = (grow == gcol) ? 0.0f : __expf(acc[fr][fc][r] * 10.0f);
                rp[r] += e;
                cs[fc] += e;
                pospart += (rlab[rr] == cl) ? e : 0.0f;
            }
        }
        // row sums: reduce across the 16 columns (lanes sharing a quad)
#pragma unroll
        for (int r = 0; r < 4; ++r) {
            float v = rp[r];
            v += __shfl_xor(v, 1, 64);
            v += __shfl_xor(v, 2, 64);
            v += __shfl_xor(v, 4, 64);
            v += __shfl_xor(v, 8, 64);
            if (l15 == 0)
                atomicAdd(&rowsum[row0 + wr * 64 + fr * 16 + quad * 4 + r], v);
        }
    }
    if (!diag) {
        // column sums: reduce across the 4 quads (rows of this wave's 64-row band)
#pragma unroll
        for (int fc = 0; fc < 4; ++fc) {
            float v = cs[fc];
            v += __shfl_xor(v, 16, 64);
            v += __shfl_xor(v, 32, 64);
            if (quad == 0)
                atomicAdd(&rowsum[col0 + wc * 64 + fc * 16 + l15], v);
        }
        pospart *= 2.0f;   // mirror tile (bj,bi) contributes identically
    }
#pragma unroll
    for (int m = 1; m < 64; m <<= 1) pospart += __shfl_xor(pospart, m, 64);
    if (lane == 0) posred[wave] = pospart;
    __syncthreads();
    if (tid == 0)
        atomicAdd(possum, posred[0] + posred[1] + posred[2] + posred[3]);

    // ---- fused finalize, fence-free ----
    // Release: __syncthreads drains each wave's vmcnt (barrier semantics), and
    // device-scope atomicAdds are globally visible once complete (they execute at
    // the coherence point). NO __threadfence -> no buffer_wbl2/inv L2 thrash.
    __syncthreads();
    if (tid == 0) ticket_s = atomicAdd((unsigned int*)(rowsum + B_N + 1), 1u);
    __syncthreads();
    if (ticket_s == NBLK - 1) {
        // Acquire: agent-scope atomic loads bypass any stale L1/L2 line.
        float s = 0.f;
        for (int i = tid; i < B_N; i += 256) {
            float rv = __hip_atomic_load(&rowsum[i], __ATOMIC_RELAXED,
                                         __HIP_MEMORY_SCOPE_AGENT);
            s += logf(rv);
        }
#pragma unroll
        for (int m = 1; m < 64; m <<= 1) s += __shfl_xor(s, m, 64);
        if (lane == 0) posred[wave] = s;   // safe: all threads past previous posred use
        __syncthreads();
        if (tid == 0) {
            float ps = __hip_atomic_load(possum, __ATOMIC_RELAXED,
                                         __HIP_MEMORY_SCOPE_AGENT);
            float tot = posred[0] + posred[1] + posred[2] + posred[3];
            // loss = mean_i log(rowsum_i) - log(possum)
            out[0] = tot / (float)B_N - logf(ps);
        }
    }
}

extern "C" void kernel_launch(void* const* d_in, const int* in_sizes, int n_in,
                              void* d_out, int out_size, void* d_ws, size_t ws_size,
                              hipStream_t stream) {
    const float* features = (const float*)d_in[0];
    const int*   targets  = (const int*)d_in[1];
    float*       out      = (float*)d_out;

    // workspace layout: [bf16 fn: 8 MB][rowsum: 4096 f32][possum: 1 f32][ticket: 1 u32]
    unsigned short* fnb    = (unsigned short*)d_ws;
    float*          rowsum = (float*)((char*)d_ws + (size_t)B_N * K_D * sizeof(unsigned short));
    float*          possum = rowsum + B_N;

    normalize_bf16<<<B_N, 256, 0, stream>>>(features, fnb, rowsum);
    gemm_exp_reduce<<<NBLK, 256, 0, stream>>>(fnb, targets, rowsum, possum, out);
}

// Round 7
// 107.703 us; speedup vs baseline: 1.3790x; 1.1216x over previous
//
#include <hip/hip_runtime.h>
#include <hip/hip_bf16.h>

#define B_N  4096
#define K_D  1024
#define TILE 128
#define BK   64
#define NT   (B_N / TILE)            // 32 tile-rows
#define NBLK (NT * (NT + 1) / 2)     // 528 upper-triangular tiles

typedef __bf16 bf16x8 __attribute__((ext_vector_type(8)));
typedef float  f32x4  __attribute__((ext_vector_type(4)));

// round-to-nearest-even float -> bf16 bits (inputs are finite normals; no NaN path needed)
__device__ __forceinline__ unsigned short f2bf(float x) {
    union { float f; unsigned int u; } v; v.f = x;
    unsigned int r = v.u + 0x7fffu + ((v.u >> 16) & 1u);
    return (unsigned short)(r >> 16);
}

// One block (256 threads) per row: compute L2 norm, write bf16 normalized row.
// Also zeroes rowsum[row] (and possum) so no separate memset node is needed.
__global__ void normalize_bf16(const float* __restrict__ f, unsigned short* __restrict__ fnb,
                               float* __restrict__ rowsum) {
    const int row = blockIdx.x;
    const int tid = threadIdx.x;
    float4 v = ((const float4*)(f + (size_t)row * K_D))[tid];
    float s = v.x * v.x + v.y * v.y + v.z * v.z + v.w * v.w;
#pragma unroll
    for (int m = 1; m < 64; m <<= 1) s += __shfl_xor(s, m, 64);
    __shared__ float wsum[4];
    if ((tid & 63) == 0) wsum[tid >> 6] = s;
    __syncthreads();
    float tot = wsum[0] + wsum[1] + wsum[2] + wsum[3];
    float scale = 1.0f / fmaxf(sqrtf(tot), 1e-12f);
    ushort4 o;
    o.x = f2bf(v.x * scale); o.y = f2bf(v.y * scale);
    o.z = f2bf(v.z * scale); o.w = f2bf(v.w * scale);
    ((ushort4*)(fnb + (size_t)row * K_D))[tid] = o;
    if (tid == 0) rowsum[row] = 0.0f;
    if (row == 0 && tid == 1) rowsum[B_N] = 0.0f;   // possum slot
}

// Upper-triangular 128x128 tiles of sim = fn*fn^T (symmetric). Each off-diagonal
// tile (bi<bj) is computed once and credited twice: row sums -> rowsum[row-block],
// column sums (quad-reduce) -> rowsum[col-block], pospart*2. Diagonal tiles once.
// 4 waves in 2x2; each wave owns a 64x64 quadrant = 4x4 fragments of 16x16x32 MFMA.
// This is the measured-best 107.0-us configuration (round 1): single-buffer LDS,
// __syncthreads K-loop, un-swizzled LDS (bank conflicts are regime-gated null at
// 2-phase -- round-3 A/B), separate finalize (fusion measured -16 us, rounds 5/6).
__global__ void gemm_exp_reduce(const unsigned short* __restrict__ fnb,
                                const int* __restrict__ labels,
                                float* __restrict__ rowsum,
                                float* __restrict__ possum) {
    __shared__ __align__(16) unsigned short As[TILE * BK]; // 16 KB
    __shared__ __align__(16) unsigned short Bs[TILE * BK]; // 16 KB
    __shared__ int   rlab[TILE];
    __shared__ int   clab[TILE];
    __shared__ float posred[4];

    // triangular decode: blockIdx.x -> (bi, bj) with bi <= bj
    int t  = blockIdx.x;
    int bi = 0;
    while (t >= NT - bi) { t -= NT - bi; ++bi; }
    const int  bj   = bi + t;
    const bool diag = (bi == bj);

    const int row0 = bi * TILE, col0 = bj * TILE;
    const int tid  = threadIdx.x;
    const int lane = tid & 63, wave = tid >> 6;
    const int wr = wave >> 1, wc = wave & 1;
    const int quad = lane >> 4, l15 = lane & 15;

    if (tid < TILE) rlab[tid] = labels[row0 + tid];
    else            clab[tid - TILE] = labels[col0 + tid - TILE];

    f32x4 acc[4][4];
#pragma unroll
    for (int i = 0; i < 4; ++i)
#pragma unroll
        for (int j = 0; j < 4; ++j) {
            f32x4 z = {0.f, 0.f, 0.f, 0.f};
            acc[i][j] = z;
        }

    for (int k0 = 0; k0 < K_D; k0 += BK) {
        // Stage A (rows row0..+127) and B (rows col0..+127) as [128][64] bf16.
        // Flat chunk c = it*256+tid covers elements [c*8, c*8+8): LDS dst is
        // contiguous in lane order, as global_load_lds requires.
#pragma unroll
        for (int it = 0; it < 4; ++it) {
            int c  = it * 256 + tid;
            int r  = c >> 3;
            int cc = (c & 7) << 3;
            __builtin_amdgcn_global_load_lds(
                (const unsigned int*)(fnb + (size_t)(row0 + r) * K_D + k0 + cc),
                (unsigned int*)&As[c * 8], 16, 0, 0);
            if (!diag)
                __builtin_amdgcn_global_load_lds(
                    (const unsigned int*)(fnb + (size_t)(col0 + r) * K_D + k0 + cc),
                    (unsigned int*)&Bs[c * 8], 16, 0, 0);
        }
        __syncthreads();

        const unsigned short* Bsrc = diag ? As : Bs;
#pragma unroll
        for (int kk = 0; kk < BK; kk += 32) {
            bf16x8 af[4], bf[4];
#pragma unroll
            for (int fr = 0; fr < 4; ++fr)
                af[fr] = *(const bf16x8*)&As[(wr * 64 + fr * 16 + l15) * BK + kk + quad * 8];
#pragma unroll
            for (int fc = 0; fc < 4; ++fc)
                bf[fc] = *(const bf16x8*)&Bsrc[(wc * 64 + fc * 16 + l15) * BK + kk + quad * 8];
#pragma unroll
            for (int fr = 0; fr < 4; ++fr)
#pragma unroll
                for (int fc = 0; fc < 4; ++fc)
                    acc[fr][fc] = __builtin_amdgcn_mfma_f32_16x16x32_bf16(
                        af[fr], bf[fc], acc[fr][fc], 0, 0, 0);
        }
        __syncthreads();
    }

    // Epilogue. C/D layout (m89/m91-verified): col = lane&15, row = quad*4 + reg.
    float pospart = 0.0f;
    float cs[4] = {0.f, 0.f, 0.f, 0.f};   // per-fc column sums (lane's column, over fr,r)
#pragma unroll
    for (int fr = 0; fr < 4; ++fr) {
        float rp[4] = {0.f, 0.f, 0.f, 0.f};
#pragma unroll
        for (int fc = 0; fc < 4; ++fc) {
            int c    = wc * 64 + fc * 16 + l15;
            int gcol = col0 + c;
            int cl   = clab[c];
#pragma unroll
            for (int r = 0; r < 4; ++r) {
                int rr   = wr * 64 + fr * 16 + quad * 4 + r;
                int grow = row0 + rr;
                float e  = (grow == gcol) ? 0.0f : __expf(acc[fr][fc][r] * 10.0f);
                rp[r] += e;
                cs[fc] += e;
                pospart += (rlab[rr] == cl) ? e : 0.0f;
            }
        }
        // row sums: reduce across the 16 columns (lanes sharing a quad)
#pragma unroll
        for (int r = 0; r < 4; ++r) {
            float v = rp[r];
            v += __shfl_xor(v, 1, 64);
            v += __shfl_xor(v, 2, 64);
            v += __shfl_xor(v, 4, 64);
            v += __shfl_xor(v, 8, 64);
            if (l15 == 0)
                atomicAdd(&rowsum[row0 + wr * 64 + fr * 16 + quad * 4 + r], v);
        }
    }
    if (!diag) {
        // column sums: reduce across the 4 quads (rows of this wave's 64-row band)
#pragma unroll
        for (int fc = 0; fc < 4; ++fc) {
            float v = cs[fc];
            v += __shfl_xor(v, 16, 64);
            v += __shfl_xor(v, 32, 64);
            if (quad == 0)
                atomicAdd(&rowsum[col0 + wc * 64 + fc * 16 + l15], v);
        }
        pospart *= 2.0f;   // mirror tile (bj,bi) contributes identically
    }
#pragma unroll
    for (int m = 1; m < 64; m <<= 1) pospart += __shfl_xor(pospart, m, 64);
    if (lane == 0) posred[wave] = pospart;
    __syncthreads();
    if (tid == 0)
        atomicAdd(possum, posred[0] + posred[1] + posred[2] + posred[3]);
}

__global__ void finalize(const float* __restrict__ rowsum,
                         const float* __restrict__ possum,
                         float* __restrict__ out) {
    const int tid = threadIdx.x;
    float s = 0.f;
    for (int i = tid; i < B_N; i += 256) s += logf(rowsum[i]);
#pragma unroll
    for (int m = 1; m < 64; m <<= 1) s += __shfl_xor(s, m, 64);
    __shared__ float w[4];
    if ((tid & 63) == 0) w[tid >> 6] = s;
    __syncthreads();
    if (tid == 0) {
        float tot = w[0] + w[1] + w[2] + w[3];
        // loss = mean_i log(rowsum_i)  -  log(possum)
        out[0] = tot / (float)B_N - logf(possum[0]);
    }
}

extern "C" void kernel_launch(void* const* d_in, const int* in_sizes, int n_in,
                              void* d_out, int out_size, void* d_ws, size_t ws_size,
                              hipStream_t stream) {
    const float* features = (const float*)d_in[0];
    const int*   targets  = (const int*)d_in[1];
    float*       out      = (float*)d_out;

    // workspace layout: [bf16 fn: 8 MB][rowsum: 4096 f32][possum: 1 f32]
    unsigned short* fnb    = (unsigned short*)d_ws;
    float*          rowsum = (float*)((char*)d_ws + (size_t)B_N * K_D * sizeof(unsigned short));
    float*          possum = rowsum + B_N;

    normalize_bf16<<<B_N, 256, 0, stream>>>(features, fnb, rowsum);
    gemm_exp_reduce<<<NBLK, 256, 0, stream>>>(fnb, targets, rowsum, possum);
    finalize<<<1, 256, 0, stream>>>(rowsum, possum, out);
}